// Round 6
// baseline (1275.411 us; speedup 1.0000x reference)
//
#include <hip/hip_runtime.h>
#include <math.h>

#define N_NODES   100000
#define N_EDGES   1600000
#define VOCAB     2048
#define NODE_DIM  64
#define HIDDEN    64
#define N_MASK    10000

#define BN        192            // nodes per bucket (192*64*4 = 49,152 B LDS)
#define NBKT      521            // ceil(100000/192)
#define CHUNK     8192           // edges per scatter block
#define NCH       196            // ceil(N_EDGES/CHUNK)

typedef __attribute__((ext_vector_type(8))) short short8;
typedef __attribute__((ext_vector_type(4))) float f32x4;
typedef unsigned short ushort_t;
typedef unsigned int uint_t;

// ---------------- workspace layout (bytes), 16-aligned ----------------
#define H1_OFF      0            // 100000*64 f32  = 25,600,000
#define X2B_OFF     25600000     // 10000*128 bf16 =  2,560,000
#define W2T_OFF     28160000     // 2048*128 bf16  =    524,288
#define EWL_OFF     28684288     // 2048*64 f32    =    524,288
#define EWR_OFF     29208576     // 2048*64 f32    =    524,288
#define E2_OFF      29732864     // 1.6M int2      = 12,800,000
#define A2C_OFF     42532864     // 10000*64 f32   =  2,560,000
#define FIDX_OFF    45092864     // 100000 i32     =    400,000
#define BCNT_OFF    45492864     // 521 i32 (pad 2112)
#define BPTR_OFF    45494976     // 522 i32 (pad 2112)
#define BCUR_OFF    45497088     // 521 i32
// total ~45.5 MB

__device__ __forceinline__ ushort_t f2bf(float f) {
    uint_t u = __builtin_bit_cast(uint_t, f);
    u += 0x7FFFu + ((u >> 16) & 1u);        // round-to-nearest-even
    return (ushort_t)(u >> 16);
}

// blocks [0,512): embWl = emb @ Wl1 ; [512,1024): embWr = emb @ Wr1
__global__ __launch_bounds__(256) void k_embw2(const float* __restrict__ emb,
                                               const float* __restrict__ Wa,
                                               const float* __restrict__ Wb,
                                               float* __restrict__ outa,
                                               float* __restrict__ outb) {
    const int half = blockIdx.x >> 9;
    const float* W = half ? Wb : Wa;
    float* out = half ? outb : outa;
    int idx = (blockIdx.x & 511) * 256 + threadIdx.x;
    int v = idx >> 6, c = idx & 63;
    float s = 0.0f;
#pragma unroll 8
    for (int k = 0; k < 64; k++) s += emb[v * 64 + k] * W[k * 64 + c];
    out[idx] = s;
}

// W2T[n][k] = bf16( k<64 ? Wl2[k][n] : Wr2[k-64][n] ),  [2048][128]
__global__ __launch_bounds__(256) void k_w2t(const float* __restrict__ Wl2,
                                             const float* __restrict__ Wr2,
                                             ushort_t* __restrict__ W2T) {
    __shared__ ushort_t T[64 * 66];
    const int k0 = blockIdx.x * 64;
    const int n0 = blockIdx.y * 64;
    const float* Wsrc = (k0 == 0) ? Wl2 : Wr2;
    const int tid = threadIdx.x;
#pragma unroll
    for (int i = 0; i < 16; i++) {
        int idx = i * 256 + tid;
        int k = idx >> 6, n = idx & 63;
        T[n * 66 + k] = f2bf(Wsrc[(size_t)k * VOCAB + n0 + n]);
    }
    __syncthreads();
#pragma unroll
    for (int i = 0; i < 16; i++) {
        int idx = i * 256 + tid;
        int n = idx >> 6, k = idx & 63;
        W2T[(size_t)(n0 + n) * 128 + k0 + k] = T[n * 66 + k];
    }
}

// pass 1a: bucket histogram (LDS-staged, one global atomic per bucket per block)
__global__ __launch_bounds__(256) void k_count(const int* __restrict__ dst,
                                               int* __restrict__ bcnt) {
    __shared__ int hist[NBKT];
    for (int i = threadIdx.x; i < NBKT; i += 256) hist[i] = 0;
    __syncthreads();
    int stride = gridDim.x * 256;
    for (int e = blockIdx.x * 256 + threadIdx.x; e < N_EDGES; e += stride)
        atomicAdd(&hist[dst[e] / BN], 1);
    __syncthreads();
    for (int i = threadIdx.x; i < NBKT; i += 256) {
        int c = hist[i];
        if (c) atomicAdd(&bcnt[i], c);
    }
}

// exclusive scan of 521 bucket counts -> bptr (and working copy bcur)
__global__ __launch_bounds__(1024) void k_bscan(const int* __restrict__ bcnt,
                                                int* __restrict__ bptr,
                                                int* __restrict__ bcur) {
    __shared__ int s[1024];
    int t = threadIdx.x;
    int v = (t < NBKT) ? bcnt[t] : 0;
    s[t] = v;
    __syncthreads();
    for (int off = 1; off < 1024; off <<= 1) {
        int a = (t >= off) ? s[t - off] : 0;
        __syncthreads();
        s[t] += a;
        __syncthreads();
    }
    if (t < NBKT) { bptr[t] = s[t] - v; bcur[t] = s[t] - v; }
    if (t == NBKT - 1) bptr[NBKT] = s[t];
}

// pass 1b: partition edges into bucket-contiguous e2 = (src, voc<<8 | dst%BN).
// Per block per bucket the writes land in one contiguous reserved run
// (~16 int2 = 128 B) -> write combining, unlike the old cursor-random k_fill.
__global__ __launch_bounds__(256) void k_scatter2(const int* __restrict__ src,
                                                  const int* __restrict__ dst,
                                                  const int* __restrict__ x,
                                                  int* __restrict__ bcur,
                                                  int2* __restrict__ e2) {
    __shared__ uint_t dstb[CHUNK];   // (b<<8) | dlow
    __shared__ int hist[NBKT];
    const int e0 = blockIdx.x * CHUNK;
    const int n = min(CHUNK, N_EDGES - e0);
    for (int i = threadIdx.x; i < NBKT; i += 256) hist[i] = 0;
    __syncthreads();
    for (int i = threadIdx.x; i < n; i += 256) {
        int d = dst[e0 + i];
        int b = d / BN;                       // compile-time magic-mul
        dstb[i] = ((uint_t)b << 8) | (uint_t)(d - b * BN);
        atomicAdd(&hist[b], 1);
    }
    __syncthreads();
    for (int i = threadIdx.x; i < NBKT; i += 256) {
        int c = hist[i];
        hist[i] = c ? atomicAdd(&bcur[i], c) : 0;   // becomes write cursor
    }
    __syncthreads();
    for (int i = threadIdx.x; i < n; i += 256) {
        uint_t db = dstb[i];
        int b = db >> 8;
        int s = src[e0 + i];
        int voc = x[s];
        int pos = atomicAdd(&hist[b], 1);
        e2[pos] = make_int2(s, (voc << 8) | (int)(db & 255u));
    }
}

// layer-1 aggregation + fused SAGE epilogue, one block per bucket.
// LDS accumulator 192x64 f32; edge-parallel (wave per edge, lane per feature),
// LDS float atomics (2 lanes/bank = free). deg from LDS counter.
__global__ __launch_bounds__(256) void k_bagg1(const int* __restrict__ bptr,
                                               const int2* __restrict__ e2,
                                               const int* __restrict__ x,
                                               const float* __restrict__ embWl,
                                               const float* __restrict__ embWr,
                                               const float* __restrict__ b1,
                                               float* __restrict__ h1) {
    __shared__ float agg[BN * 64];
    __shared__ int cnt[BN];
    const int b = blockIdx.x;
    for (int i = threadIdx.x; i < BN * 64; i += 256) agg[i] = 0.0f;
    for (int i = threadIdx.x; i < BN; i += 256) cnt[i] = 0;
    __syncthreads();
    const int r0 = bptr[b], r1 = bptr[b + 1];
    const int j = threadIdx.x & 63;
    const int w = threadIdx.x >> 6;           // 4 waves round-robin over edges
    int e = r0 + w;
    if (e < r1) {
        int2 ev = e2[e];
        for (e += 4; e < r1; e += 4) {
            int2 evn = e2[e];                  // prefetch next descriptor
            int voc = ev.y >> 8, dlow = ev.y & 255;
            atomicAdd(&agg[dlow * 64 + j], embWl[(voc << 6) + j]);
            if (j == 0) atomicAdd(&cnt[dlow], 1);
            ev = evn;
        }
        int voc = ev.y >> 8, dlow = ev.y & 255;
        atomicAdd(&agg[dlow * 64 + j], embWl[(voc << 6) + j]);
        if (j == 0) atomicAdd(&cnt[dlow], 1);
    }
    __syncthreads();
    const int base = b * BN;
    for (int idx = threadIdx.x; idx < BN * 64; idx += 256) {
        int nl = idx >> 6, jj = idx & 63;
        int node = base + nl;
        if (node < N_NODES) {
            float mean = agg[idx] * (1.0f / fmaxf((float)cnt[nl], 1.0f));
            float v = mean + embWr[(x[node] << 6) + jj] + b1[jj];
            h1[((size_t)node << 6) + jj] = fmaxf(v, 0.0f);
        }
    }
}

__global__ __launch_bounds__(256) void k_flagset(const int* __restrict__ mask,
                                                 int* __restrict__ fidx) {
    int m = blockIdx.x * 256 + threadIdx.x;
    if (m < N_MASK) fidx[mask[m]] = m;       // dup nodes: last writer wins
}

// layer-2 aggregation for masked destinations only, same bucket structure.
// ~90% of edges take the wave-uniform skip (only the 8B e2 read).
__global__ __launch_bounds__(256) void k_bagg2(const int* __restrict__ bptr,
                                               const int2* __restrict__ e2,
                                               const int* __restrict__ fidx,
                                               const float* __restrict__ h1,
                                               float* __restrict__ a2c) {
    __shared__ float agg[BN * 64];
    __shared__ int cnt[BN];
    __shared__ int flg[BN];
    const int b = blockIdx.x;
    const int base = b * BN;
    for (int i = threadIdx.x; i < BN * 64; i += 256) agg[i] = 0.0f;
    for (int i = threadIdx.x; i < BN; i += 256) {
        cnt[i] = 0;
        int node = base + i;
        flg[i] = (node < N_NODES) ? fidx[node] : -1;
    }
    __syncthreads();
    const int r0 = bptr[b], r1 = bptr[b + 1];
    const int j = threadIdx.x & 63;
    const int w = threadIdx.x >> 6;
    for (int e = r0 + w; e < r1; e += 4) {
        int2 ev = e2[e];
        int dlow = ev.y & 255;
        if (flg[dlow] < 0) continue;          // wave-uniform
        atomicAdd(&agg[dlow * 64 + j], h1[((size_t)ev.x << 6) + j]);
        if (j == 0) atomicAdd(&cnt[dlow], 1);
    }
    __syncthreads();
    for (int idx = threadIdx.x; idx < BN * 64; idx += 256) {
        int nl = idx >> 6, jj = idx & 63;
        int m = flg[nl];
        if (m >= 0)
            a2c[((size_t)m << 6) + jj] =
                agg[idx] * (1.0f / fmaxf((float)cnt[nl], 1.0f));
    }
}

// X2b[m] = bf16[ a2c[fidx[mask[m]]] | h1[mask[m]] ]
__global__ __launch_bounds__(256) void k_x2b(const int* __restrict__ mask,
                                             const int* __restrict__ fidx,
                                             const float* __restrict__ a2c,
                                             const float* __restrict__ h1,
                                             ushort_t* __restrict__ X2b) {
    int gid = blockIdx.x * 256 + threadIdx.x;
    int m = gid >> 6, j = gid & 63;
    if (m >= N_MASK) return;
    int n = mask[m];
    int mw = fidx[n];
    X2b[m * 128 + j]      = f2bf(a2c[((size_t)mw << 6) + j]);
    X2b[m * 128 + 64 + j] = f2bf(h1[((size_t)n << 6) + j]);
}

// out[R][c] = b2[c] + X2[R] . W2T[c]   via bf16 MFMA, fp32 accumulate.
__global__ __launch_bounds__(256) void k_gemm2_mfma(const ushort_t* __restrict__ X2b,
                                                    const ushort_t* __restrict__ W2T,
                                                    const float* __restrict__ bias,
                                                    float* __restrict__ out,
                                                    int M) {
    __shared__ ushort_t As[64 * 144];
    __shared__ ushort_t Bs[64 * 144];
    const int tid  = threadIdx.x;
    const int row0 = blockIdx.x * 64;
    const int col0 = blockIdx.y * 64;

#pragma unroll
    for (int i = 0; i < 4; i++) {
        int idx = i * 256 + tid;
        int r = idx >> 4, ch = idx & 15;
        int R = row0 + r;
        short8 v = {0, 0, 0, 0, 0, 0, 0, 0};
        if (R < M) v = *(const short8*)(X2b + (size_t)R * 128 + ch * 8);
        *(short8*)(As + r * 144 + ch * 8) = v;
    }
#pragma unroll
    for (int i = 0; i < 4; i++) {
        int idx = i * 256 + tid;
        int r = idx >> 4, ch = idx & 15;
        *(short8*)(Bs + r * 144 + ch * 8) =
            *(const short8*)(W2T + (size_t)(col0 + r) * 128 + ch * 8);
    }
    __syncthreads();

    const int lane = tid & 63;
    const int wv   = tid >> 6;
    const int wr = wv >> 1, wc = wv & 1;
    const int l15 = lane & 15, q = lane >> 4;

    f32x4 acc[2][2] = {};
    const ushort_t* Abase = As + (wr * 32 + l15) * 144 + q * 8;
    const ushort_t* Bbase = Bs + (wc * 32 + l15) * 144 + q * 8;

#pragma unroll
    for (int ks = 0; ks < 4; ks++) {
        short8 a0 = *(const short8*)(Abase + ks * 32);
        short8 a1 = *(const short8*)(Abase + 16 * 144 + ks * 32);
        short8 b0 = *(const short8*)(Bbase + ks * 32);
        short8 b1 = *(const short8*)(Bbase + 16 * 144 + ks * 32);
        acc[0][0] = __builtin_amdgcn_mfma_f32_16x16x32_bf16(a0, b0, acc[0][0], 0, 0, 0);
        acc[0][1] = __builtin_amdgcn_mfma_f32_16x16x32_bf16(a0, b1, acc[0][1], 0, 0, 0);
        acc[1][0] = __builtin_amdgcn_mfma_f32_16x16x32_bf16(a1, b0, acc[1][0], 0, 0, 0);
        acc[1][1] = __builtin_amdgcn_mfma_f32_16x16x32_bf16(a1, b1, acc[1][1], 0, 0, 0);
    }

    // C/D layout: col = lane&15, row = (lane>>4)*4 + reg  [verified m89/m91]
#pragma unroll
    for (int ni = 0; ni < 2; ni++) {
        int c_ = col0 + wc * 32 + ni * 16 + l15;
        float bv = bias[c_];
#pragma unroll
        for (int mi = 0; mi < 2; mi++) {
#pragma unroll
            for (int reg = 0; reg < 4; reg++) {
                int r_ = row0 + wr * 32 + mi * 16 + q * 4 + reg;
                if (r_ < M) out[(size_t)r_ * VOCAB + c_] = acc[mi][ni][reg] + bv;
            }
        }
    }
}

__global__ __launch_bounds__(256) void k_logsoftmax(float* __restrict__ out) {
    const int row = blockIdx.x;
    float4* p4 = (float4*)(out + (size_t)row * VOCAB);
    const int tid = threadIdx.x;
    float4 v[2];
    float m = -INFINITY;
#pragma unroll
    for (int i = 0; i < 2; i++) {
        v[i] = p4[tid + i * 256];
        m = fmaxf(m, fmaxf(fmaxf(v[i].x, v[i].y), fmaxf(v[i].z, v[i].w)));
    }
#pragma unroll
    for (int off = 1; off < 64; off <<= 1) m = fmaxf(m, __shfl_xor(m, off));
    __shared__ float redm[4];
    __shared__ float reds[4];
    int wave = tid >> 6;
    if ((tid & 63) == 0) redm[wave] = m;
    __syncthreads();
    m = fmaxf(fmaxf(redm[0], redm[1]), fmaxf(redm[2], redm[3]));
    float s = 0.0f;
#pragma unroll
    for (int i = 0; i < 2; i++)
        s += expf(v[i].x - m) + expf(v[i].y - m) + expf(v[i].z - m) + expf(v[i].w - m);
#pragma unroll
    for (int off = 1; off < 64; off <<= 1) s += __shfl_xor(s, off);
    if ((tid & 63) == 0) reds[wave] = s;
    __syncthreads();
    s = reds[0] + reds[1] + reds[2] + reds[3];
    float L = m + logf(s);
#pragma unroll
    for (int i = 0; i < 2; i++) {
        float4 o = v[i];
        o.x -= L; o.y -= L; o.z -= L; o.w -= L;
        p4[tid + i * 256] = o;
    }
}

extern "C" void kernel_launch(void* const* d_in, const int* in_sizes, int n_in,
                              void* d_out, int out_size, void* d_ws, size_t ws_size,
                              hipStream_t stream) {
    const int*   x    = (const int*)d_in[0];
    const int*   ei   = (const int*)d_in[1];
    const int*   src  = ei;
    const int*   dst  = ei + N_EDGES;
    const int*   mask = (const int*)d_in[2];
    const float* emb  = (const float*)d_in[3];
    const float* Wl1  = (const float*)d_in[4];
    const float* bl1  = (const float*)d_in[5];
    const float* Wr1  = (const float*)d_in[6];
    const float* Wl2  = (const float*)d_in[7];
    const float* bl2  = (const float*)d_in[8];
    const float* Wr2  = (const float*)d_in[9];
    float* out = (float*)d_out;

    char* ws = (char*)d_ws;
    float*    h1     = (float*)(ws + H1_OFF);
    ushort_t* X2b    = (ushort_t*)(ws + X2B_OFF);
    ushort_t* W2T    = (ushort_t*)(ws + W2T_OFF);
    float*    embWl  = (float*)(ws + EWL_OFF);
    float*    embWr  = (float*)(ws + EWR_OFF);
    int2*     e2     = (int2*)(ws + E2_OFF);
    float*    a2c    = (float*)(ws + A2C_OFF);
    int*      fidx   = (int*)(ws + FIDX_OFF);
    int*      bcnt   = (int*)(ws + BCNT_OFF);
    int*      bptr   = (int*)(ws + BPTR_OFF);
    int*      bcur   = (int*)(ws + BCUR_OFF);

    hipMemsetAsync(ws + BCNT_OFF, 0, 2112, stream);          // bucket counts = 0
    hipMemsetAsync(ws + FIDX_OFF, 0xFF, 400000, stream);     // flagidx = -1

    k_embw2<<<1024, 256, 0, stream>>>(emb, Wl1, Wr1, embWl, embWr);
    dim3 gw2(2, VOCAB / 64);
    k_w2t<<<gw2, 256, 0, stream>>>(Wl2, Wr2, W2T);

    // bucket partition (radix-1 by dst/BN)
    k_count   <<<512, 256, 0, stream>>>(dst, bcnt);
    k_bscan   <<<1, 1024, 0, stream>>>(bcnt, bptr, bcur);
    k_scatter2<<<NCH, 256, 0, stream>>>(src, dst, x, bcur, e2);

    // layer 1: bucket-local LDS aggregation + fused epilogue
    k_bagg1<<<NBKT, 256, 0, stream>>>(bptr, e2, x, embWl, embWr, bl1, h1);

    // layer 2: masked-dst bucket aggregation, then X2 assembly + MFMA GEMM
    k_flagset<<<(N_MASK + 255) / 256, 256, 0, stream>>>(mask, fidx);
    k_bagg2<<<NBKT, 256, 0, stream>>>(bptr, e2, fidx, h1, a2c);
    k_x2b<<<(N_MASK * 64 + 255) / 256, 256, 0, stream>>>(mask, fidx, a2c, h1, X2b);
    dim3 g2((N_MASK + 63) / 64, VOCAB / 64);
    k_gemm2_mfma<<<g2, 256, 0, stream>>>(X2b, W2T, bl2, out, N_MASK);

    k_logsoftmax<<<N_MASK, 256, 0, stream>>>(out);
}

// Round 7
// 322.324 us; speedup vs baseline: 3.9569x; 3.9569x over previous
//
#include <hip/hip_runtime.h>
#include <math.h>

#define N_NODES   100000
#define N_EDGES   1600000
#define VOCAB     2048
#define NODE_DIM  64
#define HIDDEN    64
#define N_MASK    10000

#define BN        192            // nodes per bucket
#define NBKT      521            // ceil(100000/192)
#define CHUNK     8192           // edges per partition block
#define NCH       196            // ceil(N_EDGES/CHUNK)

typedef __attribute__((ext_vector_type(8))) short short8;
typedef __attribute__((ext_vector_type(4))) float f32x4;
typedef unsigned short ushort_t;
typedef unsigned int uint_t;

// ---------------- workspace layout (bytes), 16-aligned ----------------
// e2 (bucket-partitioned edges) dies after k_sortb; embW tables, W2T and X2b
// alias its region (they are created strictly after k_sortb).
#define H1_OFF      0            // 100000*64 f32  = 25,600,000
#define E3_OFF      25600000     // 1.6M int2      = 12,800,000  (CSR-sorted)
#define E2_OFF      38400000     // 1.6M int2      = 12,800,000  (dead after sortb)
#define EWL_OFF     38400000     //   2048*64 f32  =    524,288  (aliases e2)
#define EWR_OFF     38924288     //   2048*64 f32  =    524,288
#define W2T_OFF     39448576     //   2048*128 bf16=    524,288
#define X2B_OFF     39972864     //   10000*128 bf16=  2,560,000
#define ROWPTR_OFF  51200000     // 100001 i32
#define BCNT_OFF    51600016     // 521 i32
#define BPTR_OFF    51602112     // 522 i32
#define BCUR_OFF    51604208     // 521 i32
// total ~51.61 MB

__device__ __forceinline__ ushort_t f2bf(float f) {
    uint_t u = __builtin_bit_cast(uint_t, f);
    u += 0x7FFFu + ((u >> 16) & 1u);        // round-to-nearest-even
    return (ushort_t)(u >> 16);
}

// blocks [0,512): embWl = emb @ Wl1 ; [512,1024): embWr = emb @ Wr1
__global__ __launch_bounds__(256) void k_embw2(const float* __restrict__ emb,
                                               const float* __restrict__ Wa,
                                               const float* __restrict__ Wb,
                                               float* __restrict__ outa,
                                               float* __restrict__ outb) {
    const int half = blockIdx.x >> 9;
    const float* W = half ? Wb : Wa;
    float* out = half ? outb : outa;
    int idx = (blockIdx.x & 511) * 256 + threadIdx.x;
    int v = idx >> 6, c = idx & 63;
    float s = 0.0f;
#pragma unroll 8
    for (int k = 0; k < 64; k++) s += emb[v * 64 + k] * W[k * 64 + c];
    out[idx] = s;
}

// W2T[n][k] = bf16( k<64 ? Wl2[k][n] : Wr2[k-64][n] ),  [2048][128]
__global__ __launch_bounds__(256) void k_w2t(const float* __restrict__ Wl2,
                                             const float* __restrict__ Wr2,
                                             ushort_t* __restrict__ W2T) {
    __shared__ ushort_t T[64 * 66];
    const int k0 = blockIdx.x * 64;
    const int n0 = blockIdx.y * 64;
    const float* Wsrc = (k0 == 0) ? Wl2 : Wr2;
    const int tid = threadIdx.x;
#pragma unroll
    for (int i = 0; i < 16; i++) {
        int idx = i * 256 + tid;
        int k = idx >> 6, n = idx & 63;
        T[n * 66 + k] = f2bf(Wsrc[(size_t)k * VOCAB + n0 + n]);
    }
    __syncthreads();
#pragma unroll
    for (int i = 0; i < 16; i++) {
        int idx = i * 256 + tid;
        int n = idx >> 6, k = idx & 63;
        W2T[(size_t)(n0 + n) * 128 + k0 + k] = T[n * 66 + k];
    }
}

// bucket histogram (LDS-staged, one global atomic per bucket per block)
__global__ __launch_bounds__(256) void k_count(const int* __restrict__ dst,
                                               int* __restrict__ bcnt) {
    __shared__ int hist[NBKT];
    for (int i = threadIdx.x; i < NBKT; i += 256) hist[i] = 0;
    __syncthreads();
    int stride = gridDim.x * 256;
    for (int e = blockIdx.x * 256 + threadIdx.x; e < N_EDGES; e += stride)
        atomicAdd(&hist[dst[e] / BN], 1);
    __syncthreads();
    for (int i = threadIdx.x; i < NBKT; i += 256) {
        int c = hist[i];
        if (c) atomicAdd(&bcnt[i], c);
    }
}

// exclusive scan of 521 bucket counts -> bptr, bcur; rowptr[N] = N_EDGES
__global__ __launch_bounds__(1024) void k_bscan(const int* __restrict__ bcnt,
                                                int* __restrict__ bptr,
                                                int* __restrict__ bcur,
                                                int* __restrict__ rowptr) {
    __shared__ int s[1024];
    int t = threadIdx.x;
    int v = (t < NBKT) ? bcnt[t] : 0;
    s[t] = v;
    __syncthreads();
    for (int off = 1; off < 1024; off <<= 1) {
        int a = (t >= off) ? s[t - off] : 0;
        __syncthreads();
        s[t] += a;
        __syncthreads();
    }
    if (t < NBKT) { bptr[t] = s[t] - v; bcur[t] = s[t] - v; }
    if (t == NBKT - 1) bptr[NBKT] = s[t];
    if (t == 0) rowptr[N_NODES] = N_EDGES;
}

// partition edges into bucket-contiguous e2 = (src, voc<<8 | dst%BN).
// Per block per bucket the writes land in one contiguous reserved run
// (~16 int2 = 128 B) -> write combining.
__global__ __launch_bounds__(256) void k_scatter2(const int* __restrict__ src,
                                                  const int* __restrict__ dst,
                                                  const int* __restrict__ x,
                                                  int* __restrict__ bcur,
                                                  int2* __restrict__ e2) {
    __shared__ uint_t dstb[CHUNK];   // (b<<8) | dlow
    __shared__ int hist[NBKT];
    const int e0 = blockIdx.x * CHUNK;
    const int n = min(CHUNK, N_EDGES - e0);
    for (int i = threadIdx.x; i < NBKT; i += 256) hist[i] = 0;
    __syncthreads();
    for (int i = threadIdx.x; i < n; i += 256) {
        int d = dst[e0 + i];
        int b = d / BN;                       // compile-time magic-mul
        dstb[i] = ((uint_t)b << 8) | (uint_t)(d - b * BN);
        atomicAdd(&hist[b], 1);
    }
    __syncthreads();
    for (int i = threadIdx.x; i < NBKT; i += 256) {
        int c = hist[i];
        hist[i] = c ? atomicAdd(&bcur[i], c) : 0;   // becomes write cursor
    }
    __syncthreads();
    for (int i = threadIdx.x; i < n; i += 256) {
        uint_t db = dstb[i];
        int b = db >> 8;
        int s = src[e0 + i];
        int voc = x[s];
        int pos = atomicAdd(&hist[b], 1);
        e2[pos] = make_int2(s, (voc << 8) | (int)(db & 255u));
    }
}

// per-bucket LDS counting sort: builds rowptr (coalesced) and CSR-ordered
// e3 = (src, voc). Scatter stays inside the bucket's own ~24 KB window ->
// L2-resident, ~1x write amplification.
__global__ __launch_bounds__(256) void k_sortb(const int* __restrict__ bptr,
                                               const int2* __restrict__ e2,
                                               int* __restrict__ rowptr,
                                               int2* __restrict__ e3) {
    __shared__ int cnt[BN];
    __shared__ int s[256];
    __shared__ int cur[BN];
    const int b = blockIdx.x;
    const int t = threadIdx.x;
    const int r0 = bptr[b], r1 = bptr[b + 1];
    if (t < BN) cnt[t] = 0;
    __syncthreads();
    for (int e = r0 + t; e < r1; e += 256)
        atomicAdd(&cnt[e2[e].y & 255], 1);
    __syncthreads();
    int v = (t < BN) ? cnt[t] : 0;
    s[t] = v;
    __syncthreads();
    for (int off = 1; off < 256; off <<= 1) {
        int a = (t >= off) ? s[t - off] : 0;
        __syncthreads();
        s[t] += a;
        __syncthreads();
    }
    if (t < BN) {
        int excl = s[t] - v;
        cur[t] = excl;
        int node = b * BN + t;
        if (node < N_NODES) rowptr[node] = r0 + excl;
    }
    __syncthreads();
    for (int e = r0 + t; e < r1; e += 256) {
        int2 ev = e2[e];
        int pos = r0 + atomicAdd(&cur[ev.y & 255], 1);
        e3[pos] = make_int2(ev.x, ev.y >> 8);
    }
}

// h1[n] = relu( mean_e embWl[voc_e] + embWr[x[n]] + b1 ), one wave per node,
// 2-way ILP on the L2 gather chain.
__global__ __launch_bounds__(256) void k_agg1(const int* __restrict__ rowptr,
                                              const int2* __restrict__ e3,
                                              const int* __restrict__ x,
                                              const float* __restrict__ embWl,
                                              const float* __restrict__ embWr,
                                              const float* __restrict__ b1,
                                              float* __restrict__ h1) {
    int gw = (blockIdx.x * 256 + threadIdx.x) >> 6;
    int j = threadIdx.x & 63;
    if (gw >= N_NODES) return;
    int r0 = rowptr[gw], r1 = rowptr[gw + 1];
    float sum = 0.0f, sum2 = 0.0f;
    int e = r0;
    for (; e + 1 < r1; e += 2) {
        int v0 = e3[e].y, v1 = e3[e + 1].y;
        sum  += embWl[(v0 << 6) + j];
        sum2 += embWl[(v1 << 6) + j];
    }
    if (e < r1) sum += embWl[(e3[e].y << 6) + j];
    sum += sum2;
    float inv = 1.0f / fmaxf((float)(r1 - r0), 1.0f);
    float self = embWr[(x[gw] << 6) + j];
    h1[((size_t)gw << 6) + j] = fmaxf(sum * inv + self + b1[j], 0.0f);
}

// X2b[m] = bf16[ mean_e h1[src_e] | h1[mask[m]] ], one wave per masked row
__global__ __launch_bounds__(256) void k_x2(const int* __restrict__ mask,
                                            const int* __restrict__ rowptr,
                                            const int2* __restrict__ e3,
                                            const float* __restrict__ h1,
                                            ushort_t* __restrict__ X2b) {
    int gw = (blockIdx.x * 256 + threadIdx.x) >> 6;
    int j = threadIdx.x & 63;
    if (gw >= N_MASK) return;
    int n = mask[gw];
    int r0 = rowptr[n], r1 = rowptr[n + 1];
    float sum = 0.0f, sum2 = 0.0f;
    int e = r0;
    for (; e + 1 < r1; e += 2) {
        int s0 = e3[e].x, s1 = e3[e + 1].x;
        sum  += h1[((size_t)s0 << 6) + j];
        sum2 += h1[((size_t)s1 << 6) + j];
    }
    if (e < r1) sum += h1[((size_t)e3[e].x << 6) + j];
    sum += sum2;
    float inv = 1.0f / fmaxf((float)(r1 - r0), 1.0f);
    X2b[gw * 128 + j]      = f2bf(sum * inv);
    X2b[gw * 128 + 64 + j] = f2bf(h1[((size_t)n << 6) + j]);
}

// out[R][c] = b2[c] + X2[R] . W2T[c]   via bf16 MFMA, fp32 accumulate.
__global__ __launch_bounds__(256) void k_gemm2_mfma(const ushort_t* __restrict__ X2b,
                                                    const ushort_t* __restrict__ W2T,
                                                    const float* __restrict__ bias,
                                                    float* __restrict__ out,
                                                    int M) {
    __shared__ ushort_t As[64 * 144];
    __shared__ ushort_t Bs[64 * 144];
    const int tid  = threadIdx.x;
    const int row0 = blockIdx.x * 64;
    const int col0 = blockIdx.y * 64;

#pragma unroll
    for (int i = 0; i < 4; i++) {
        int idx = i * 256 + tid;
        int r = idx >> 4, ch = idx & 15;
        int R = row0 + r;
        short8 v = {0, 0, 0, 0, 0, 0, 0, 0};
        if (R < M) v = *(const short8*)(X2b + (size_t)R * 128 + ch * 8);
        *(short8*)(As + r * 144 + ch * 8) = v;
    }
#pragma unroll
    for (int i = 0; i < 4; i++) {
        int idx = i * 256 + tid;
        int r = idx >> 4, ch = idx & 15;
        *(short8*)(Bs + r * 144 + ch * 8) =
            *(const short8*)(W2T + (size_t)(col0 + r) * 128 + ch * 8);
    }
    __syncthreads();

    const int lane = tid & 63;
    const int wv   = tid >> 6;
    const int wr = wv >> 1, wc = wv & 1;
    const int l15 = lane & 15, q = lane >> 4;

    f32x4 acc[2][2] = {};
    const ushort_t* Abase = As + (wr * 32 + l15) * 144 + q * 8;
    const ushort_t* Bbase = Bs + (wc * 32 + l15) * 144 + q * 8;

#pragma unroll
    for (int ks = 0; ks < 4; ks++) {
        short8 a0 = *(const short8*)(Abase + ks * 32);
        short8 a1 = *(const short8*)(Abase + 16 * 144 + ks * 32);
        short8 b0 = *(const short8*)(Bbase + ks * 32);
        short8 b1 = *(const short8*)(Bbase + 16 * 144 + ks * 32);
        acc[0][0] = __builtin_amdgcn_mfma_f32_16x16x32_bf16(a0, b0, acc[0][0], 0, 0, 0);
        acc[0][1] = __builtin_amdgcn_mfma_f32_16x16x32_bf16(a0, b1, acc[0][1], 0, 0, 0);
        acc[1][0] = __builtin_amdgcn_mfma_f32_16x16x32_bf16(a1, b0, acc[1][0], 0, 0, 0);
        acc[1][1] = __builtin_amdgcn_mfma_f32_16x16x32_bf16(a1, b1, acc[1][1], 0, 0, 0);
    }

    // C/D layout: col = lane&15, row = (lane>>4)*4 + reg  [verified m89/m91]
#pragma unroll
    for (int ni = 0; ni < 2; ni++) {
        int c_ = col0 + wc * 32 + ni * 16 + l15;
        float bv = bias[c_];
#pragma unroll
        for (int mi = 0; mi < 2; mi++) {
#pragma unroll
            for (int reg = 0; reg < 4; reg++) {
                int r_ = row0 + wr * 32 + mi * 16 + q * 4 + reg;
                if (r_ < M) out[(size_t)r_ * VOCAB + c_] = acc[mi][ni][reg] + bv;
            }
        }
    }
}

__global__ __launch_bounds__(256) void k_logsoftmax(float* __restrict__ out) {
    const int row = blockIdx.x;
    float4* p4 = (float4*)(out + (size_t)row * VOCAB);
    const int tid = threadIdx.x;
    float4 v[2];
    float m = -INFINITY;
#pragma unroll
    for (int i = 0; i < 2; i++) {
        v[i] = p4[tid + i * 256];
        m = fmaxf(m, fmaxf(fmaxf(v[i].x, v[i].y), fmaxf(v[i].z, v[i].w)));
    }
#pragma unroll
    for (int off = 1; off < 64; off <<= 1) m = fmaxf(m, __shfl_xor(m, off));
    __shared__ float redm[4];
    __shared__ float reds[4];
    int wave = tid >> 6;
    if ((tid & 63) == 0) redm[wave] = m;
    __syncthreads();
    m = fmaxf(fmaxf(redm[0], redm[1]), fmaxf(redm[2], redm[3]));
    float s = 0.0f;
#pragma unroll
    for (int i = 0; i < 2; i++)
        s += expf(v[i].x - m) + expf(v[i].y - m) + expf(v[i].z - m) + expf(v[i].w - m);
#pragma unroll
    for (int off = 1; off < 64; off <<= 1) s += __shfl_xor(s, off);
    if ((tid & 63) == 0) reds[wave] = s;
    __syncthreads();
    s = reds[0] + reds[1] + reds[2] + reds[3];
    float L = m + logf(s);
#pragma unroll
    for (int i = 0; i < 2; i++) {
        float4 o = v[i];
        o.x -= L; o.y -= L; o.z -= L; o.w -= L;
        p4[tid + i * 256] = o;
    }
}

extern "C" void kernel_launch(void* const* d_in, const int* in_sizes, int n_in,
                              void* d_out, int out_size, void* d_ws, size_t ws_size,
                              hipStream_t stream) {
    const int*   x    = (const int*)d_in[0];
    const int*   ei   = (const int*)d_in[1];
    const int*   src  = ei;
    const int*   dst  = ei + N_EDGES;
    const int*   mask = (const int*)d_in[2];
    const float* emb  = (const float*)d_in[3];
    const float* Wl1  = (const float*)d_in[4];
    const float* bl1  = (const float*)d_in[5];
    const float* Wr1  = (const float*)d_in[6];
    const float* Wl2  = (const float*)d_in[7];
    const float* bl2  = (const float*)d_in[8];
    const float* Wr2  = (const float*)d_in[9];
    float* out = (float*)d_out;

    char* ws = (char*)d_ws;
    float*    h1     = (float*)(ws + H1_OFF);
    int2*     e3     = (int2*)(ws + E3_OFF);
    int2*     e2     = (int2*)(ws + E2_OFF);
    float*    embWl  = (float*)(ws + EWL_OFF);     // aliases e2 (after sortb)
    float*    embWr  = (float*)(ws + EWR_OFF);
    ushort_t* W2T    = (ushort_t*)(ws + W2T_OFF);
    ushort_t* X2b    = (ushort_t*)(ws + X2B_OFF);
    int*      rowptr = (int*)(ws + ROWPTR_OFF);
    int*      bcnt   = (int*)(ws + BCNT_OFF);
    int*      bptr   = (int*)(ws + BPTR_OFF);
    int*      bcur   = (int*)(ws + BCUR_OFF);

    hipMemsetAsync(ws + BCNT_OFF, 0, 2096, stream);          // bucket counts = 0

    // ---- CSR build: bucket partition + per-bucket LDS counting sort ----
    k_count   <<<512, 256, 0, stream>>>(dst, bcnt);
    k_bscan   <<<1, 1024, 0, stream>>>(bcnt, bptr, bcur, rowptr);
    k_scatter2<<<NCH, 256, 0, stream>>>(src, dst, x, bcur, e2);
    k_sortb   <<<NBKT, 256, 0, stream>>>(bptr, e2, rowptr, e3);

    // ---- small transformed tables (placed in e2's dead region) ----
    k_embw2<<<1024, 256, 0, stream>>>(emb, Wl1, Wr1, embWl, embWr);
    dim3 gw2(2, VOCAB / 64);
    k_w2t<<<gw2, 256, 0, stream>>>(Wl2, Wr2, W2T);

    // ---- layer 1: node-parallel CSR aggregation, fused epilogue ----
    k_agg1<<<(N_NODES * 64 + 255) / 256, 256, 0, stream>>>(rowptr, e3, x, embWl, embWr, bl1, h1);

    // ---- layer 2: masked-row gather -> bf16 X2, MFMA GEMM, log_softmax ----
    k_x2<<<(N_MASK * 64 + 255) / 256, 256, 0, stream>>>(mask, rowptr, e3, h1, X2b);
    dim3 g2((N_MASK + 63) / 64, VOCAB / 64);
    k_gemm2_mfma<<<g2, 256, 0, stream>>>(X2b, W2T, bl2, out, N_MASK);

    k_logsoftmax<<<N_MASK, 256, 0, stream>>>(out);
}

// Round 8
// 295.121 us; speedup vs baseline: 4.3216x; 1.0922x over previous
//
#include <hip/hip_runtime.h>
#include <math.h>

#define N_NODES   100000
#define N_EDGES   1600000
#define VOCAB     2048
#define NODE_DIM  64
#define HIDDEN    64
#define N_MASK    10000

#define BN        192            // nodes per bucket
#define NBKT      521            // ceil(100000/192)
#define CHUNK     4096           // edges per partition block
#define NCH       391            // ceil(N_EDGES/CHUNK)

typedef __attribute__((ext_vector_type(8))) short short8;
typedef __attribute__((ext_vector_type(4))) float f32x4;
typedef unsigned short ushort_t;
typedef unsigned int uint_t;

// ---------------- workspace layout (bytes), 16-aligned ----------------
// e2 (bucket-partitioned edges) dies after k_sortb; embW tables, W2T and X2b
// alias its region (created strictly after k_sortb on the same stream).
#define H1_OFF      0            // 100000*64 f32  = 25,600,000
#define ESRC_OFF    25600000     // 1.6M i32       =  6,400,000  (CSR order)
#define EVOC_OFF    32000000     // 1.6M i32       =  6,400,000  (CSR order)
#define E2_OFF      38400000     // 1.6M int2      = 12,800,000  (dead after sortb)
#define EWL_OFF     38400000     //   2048*64 f32  =    524,288  (aliases e2)
#define EWR_OFF     38924288     //   2048*64 f32  =    524,288
#define W2T_OFF     39448576     //   2048*128 bf16=    524,288
#define X2B_OFF     39972864     //   10000*128 bf16= 2,560,000
#define ROWPTR_OFF  51200000     // 100001 i32
#define BCNT_OFF    51600016     // 521 i32
#define BPTR_OFF    51602112     // 522 i32
#define BCUR_OFF    51604208     // 521 i32
// total ~51.61 MB

__device__ __forceinline__ ushort_t f2bf(float f) {
    uint_t u = __builtin_bit_cast(uint_t, f);
    u += 0x7FFFu + ((u >> 16) & 1u);        // round-to-nearest-even
    return (ushort_t)(u >> 16);
}

// one launch for all small preprocessing:
// blocks [0,512):    embWl = emb @ Wl1
// blocks [512,1024): embWr = emb @ Wr1
// blocks [1024,1088): W2T[n][k] = bf16([Wl2;Wr2]^T)
__global__ __launch_bounds__(256) void k_prep(const float* __restrict__ emb,
                                              const float* __restrict__ Wl1,
                                              const float* __restrict__ Wr1,
                                              const float* __restrict__ Wl2,
                                              const float* __restrict__ Wr2,
                                              float* __restrict__ embWl,
                                              float* __restrict__ embWr,
                                              ushort_t* __restrict__ W2T) {
    __shared__ ushort_t T[64 * 66];
    const int bx = blockIdx.x;
    const int tid = threadIdx.x;
    if (bx < 1024) {
        const int half = bx >> 9;
        const float* W = half ? Wr1 : Wl1;
        float* out = half ? embWr : embWl;
        int idx = (bx & 511) * 256 + tid;
        int v = idx >> 6, c = idx & 63;
        float s = 0.0f;
#pragma unroll 8
        for (int k = 0; k < 64; k++) s += emb[v * 64 + k] * W[k * 64 + c];
        out[idx] = s;
    } else {
        int t = bx - 1024;                    // 64 blocks: 2 k-halves x 32 n-tiles
        const int k0 = (t & 1) * 64;
        const int n0 = (t >> 1) * 64;
        const float* Wsrc = (k0 == 0) ? Wl2 : Wr2;
#pragma unroll
        for (int i = 0; i < 16; i++) {
            int idx = i * 256 + tid;
            int k = idx >> 6, n = idx & 63;
            T[n * 66 + k] = f2bf(Wsrc[(size_t)k * VOCAB + n0 + n]);
        }
        __syncthreads();
#pragma unroll
        for (int i = 0; i < 16; i++) {
            int idx = i * 256 + tid;
            int n = idx >> 6, k = idx & 63;
            W2T[(size_t)(n0 + n) * 128 + k0 + k] = T[n * 66 + k];
        }
    }
}

// bucket histogram (LDS-staged, one global atomic per bucket per block)
__global__ __launch_bounds__(256) void k_count(const int* __restrict__ dst,
                                               int* __restrict__ bcnt) {
    __shared__ int hist[NBKT];
    for (int i = threadIdx.x; i < NBKT; i += 256) hist[i] = 0;
    __syncthreads();
    int stride = gridDim.x * 256;
    for (int e = blockIdx.x * 256 + threadIdx.x; e < N_EDGES; e += stride)
        atomicAdd(&hist[dst[e] / BN], 1);
    __syncthreads();
    for (int i = threadIdx.x; i < NBKT; i += 256) {
        int c = hist[i];
        if (c) atomicAdd(&bcnt[i], c);
    }
}

// exclusive scan of 521 bucket counts -> bptr, bcur; rowptr[N] = N_EDGES
__global__ __launch_bounds__(1024) void k_bscan(const int* __restrict__ bcnt,
                                                int* __restrict__ bptr,
                                                int* __restrict__ bcur,
                                                int* __restrict__ rowptr) {
    __shared__ int s[1024];
    int t = threadIdx.x;
    int v = (t < NBKT) ? bcnt[t] : 0;
    s[t] = v;
    __syncthreads();
    for (int off = 1; off < 1024; off <<= 1) {
        int a = (t >= off) ? s[t - off] : 0;
        __syncthreads();
        s[t] += a;
        __syncthreads();
    }
    if (t < NBKT) { bptr[t] = s[t] - v; bcur[t] = s[t] - v; }
    if (t == NBKT - 1) bptr[NBKT] = s[t];
    if (t == 0) rowptr[N_NODES] = N_EDGES;
}

// partition edges into bucket-contiguous e2 = (src, voc<<8 | dst%BN).
// Per block per bucket the writes land in one contiguous reserved run ->
// write combining instead of 64B-line-per-8B-store amplification.
__global__ __launch_bounds__(256) void k_scatter2(const int* __restrict__ src,
                                                  const int* __restrict__ dst,
                                                  const int* __restrict__ x,
                                                  int* __restrict__ bcur,
                                                  int2* __restrict__ e2) {
    __shared__ uint_t dstb[CHUNK];   // (b<<8) | dlow
    __shared__ int hist[NBKT];
    const int e0 = blockIdx.x * CHUNK;
    const int n = min(CHUNK, N_EDGES - e0);
    for (int i = threadIdx.x; i < NBKT; i += 256) hist[i] = 0;
    __syncthreads();
    for (int i = threadIdx.x; i < n; i += 256) {
        int d = dst[e0 + i];
        int b = d / BN;                       // compile-time magic-mul
        dstb[i] = ((uint_t)b << 8) | (uint_t)(d - b * BN);
        atomicAdd(&hist[b], 1);
    }
    __syncthreads();
    for (int i = threadIdx.x; i < NBKT; i += 256) {
        int c = hist[i];
        hist[i] = c ? atomicAdd(&bcur[i], c) : 0;   // becomes write cursor
    }
    __syncthreads();
    for (int i = threadIdx.x; i < n; i += 256) {
        uint_t db = dstb[i];
        int b = db >> 8;
        int s = src[e0 + i];
        int voc = x[s];
        int pos = atomicAdd(&hist[b], 1);
        e2[pos] = make_int2(s, (voc << 8) | (int)(db & 255u));
    }
}

// per-bucket LDS counting sort: builds rowptr (coalesced) and CSR-ordered
// esrc/evoc. Scatter stays inside the bucket's own L2-resident window.
__global__ __launch_bounds__(256) void k_sortb(const int* __restrict__ bptr,
                                               const int2* __restrict__ e2,
                                               int* __restrict__ rowptr,
                                               int* __restrict__ esrc,
                                               int* __restrict__ evoc) {
    __shared__ int cnt[BN];
    __shared__ int s[256];
    __shared__ int cur[BN];
    const int b = blockIdx.x;
    const int t = threadIdx.x;
    const int r0 = bptr[b], r1 = bptr[b + 1];
    if (t < BN) cnt[t] = 0;
    __syncthreads();
    for (int e = r0 + t; e < r1; e += 256)
        atomicAdd(&cnt[e2[e].y & 255], 1);
    __syncthreads();
    int v = (t < BN) ? cnt[t] : 0;
    s[t] = v;
    __syncthreads();
    for (int off = 1; off < 256; off <<= 1) {
        int a = (t >= off) ? s[t - off] : 0;
        __syncthreads();
        s[t] += a;
        __syncthreads();
    }
    if (t < BN) {
        int excl = s[t] - v;
        cur[t] = excl;
        int node = b * BN + t;
        if (node < N_NODES) rowptr[node] = r0 + excl;
    }
    __syncthreads();
    for (int e = r0 + t; e < r1; e += 256) {
        int2 ev = e2[e];
        int pos = r0 + atomicAdd(&cur[ev.y & 255], 1);
        esrc[pos] = ev.x;
        evoc[pos] = ev.y >> 8;
    }
}

// h1[n] = relu( mean_e embWl[voc_e] + embWr[x[n]] + b1 ), one wave per node.
// Lane-parallel descriptor staging (one coalesced load for <=64 edges) +
// __shfl broadcast: the vocab index comes from registers, so the embWl
// gathers are the ONLY memory ops on the critical path, issued 4-wide.
__global__ __launch_bounds__(256) void k_agg1(const int* __restrict__ rowptr,
                                              const int* __restrict__ evoc,
                                              const int* __restrict__ x,
                                              const float* __restrict__ embWl,
                                              const float* __restrict__ embWr,
                                              const float* __restrict__ b1,
                                              float* __restrict__ h1) {
    int gw = (blockIdx.x * 256 + threadIdx.x) >> 6;
    int lane = threadIdx.x & 63;
    if (gw >= N_NODES) return;
    int r0 = rowptr[gw], r1 = rowptr[gw + 1];
    int deg = r1 - r0;
    float s0 = 0.0f, s1 = 0.0f, s2 = 0.0f, s3 = 0.0f;
    for (int base = 0; base < deg; base += 64) {
        int cnt = min(64, deg - base);
        int myv = (base + lane < deg) ? evoc[r0 + base + lane] : 0;
        int t = 0;
        for (; t + 3 < cnt; t += 4) {
            int va = __shfl(myv, t);
            int vb = __shfl(myv, t + 1);
            int vc = __shfl(myv, t + 2);
            int vd = __shfl(myv, t + 3);
            s0 += embWl[(va << 6) + lane];
            s1 += embWl[(vb << 6) + lane];
            s2 += embWl[(vc << 6) + lane];
            s3 += embWl[(vd << 6) + lane];
        }
        for (; t < cnt; t++)
            s0 += embWl[(__shfl(myv, t) << 6) + lane];
    }
    float sum = (s0 + s1) + (s2 + s3);
    float inv = 1.0f / fmaxf((float)deg, 1.0f);
    float self = embWr[(x[gw] << 6) + lane];
    h1[((size_t)gw << 6) + lane] = fmaxf(sum * inv + self + b1[lane], 0.0f);
}

// X2b[m] = bf16[ mean_e h1[src_e] | h1[mask[m]] ], one wave per masked row,
// same staged-descriptor + shuffle structure.
__global__ __launch_bounds__(256) void k_x2(const int* __restrict__ mask,
                                            const int* __restrict__ rowptr,
                                            const int* __restrict__ esrc,
                                            const float* __restrict__ h1,
                                            ushort_t* __restrict__ X2b) {
    int gw = (blockIdx.x * 256 + threadIdx.x) >> 6;
    int lane = threadIdx.x & 63;
    if (gw >= N_MASK) return;
    int n = mask[gw];
    int r0 = rowptr[n], r1 = rowptr[n + 1];
    int deg = r1 - r0;
    float s0 = 0.0f, s1 = 0.0f, s2 = 0.0f, s3 = 0.0f;
    for (int base = 0; base < deg; base += 64) {
        int cnt = min(64, deg - base);
        int mys = (base + lane < deg) ? esrc[r0 + base + lane] : 0;
        int t = 0;
        for (; t + 3 < cnt; t += 4) {
            int sa = __shfl(mys, t);
            int sb = __shfl(mys, t + 1);
            int sc = __shfl(mys, t + 2);
            int sd = __shfl(mys, t + 3);
            s0 += h1[((size_t)sa << 6) + lane];
            s1 += h1[((size_t)sb << 6) + lane];
            s2 += h1[((size_t)sc << 6) + lane];
            s3 += h1[((size_t)sd << 6) + lane];
        }
        for (; t < cnt; t++)
            s0 += h1[((size_t)__shfl(mys, t) << 6) + lane];
    }
    float sum = (s0 + s1) + (s2 + s3);
    float inv = 1.0f / fmaxf((float)deg, 1.0f);
    X2b[gw * 128 + lane]      = f2bf(sum * inv);
    X2b[gw * 128 + 64 + lane] = f2bf(h1[((size_t)n << 6) + lane]);
}

// out[R][c] = b2[c] + X2[R] . W2T[c]   via bf16 MFMA, fp32 accumulate.
__global__ __launch_bounds__(256) void k_gemm2_mfma(const ushort_t* __restrict__ X2b,
                                                    const ushort_t* __restrict__ W2T,
                                                    const float* __restrict__ bias,
                                                    float* __restrict__ out,
                                                    int M) {
    __shared__ ushort_t As[64 * 144];
    __shared__ ushort_t Bs[64 * 144];
    const int tid  = threadIdx.x;
    const int row0 = blockIdx.x * 64;
    const int col0 = blockIdx.y * 64;

#pragma unroll
    for (int i = 0; i < 4; i++) {
        int idx = i * 256 + tid;
        int r = idx >> 4, ch = idx & 15;
        int R = row0 + r;
        short8 v = {0, 0, 0, 0, 0, 0, 0, 0};
        if (R < M) v = *(const short8*)(X2b + (size_t)R * 128 + ch * 8);
        *(short8*)(As + r * 144 + ch * 8) = v;
    }
#pragma unroll
    for (int i = 0; i < 4; i++) {
        int idx = i * 256 + tid;
        int r = idx >> 4, ch = idx & 15;
        *(short8*)(Bs + r * 144 + ch * 8) =
            *(const short8*)(W2T + (size_t)(col0 + r) * 128 + ch * 8);
    }
    __syncthreads();

    const int lane = tid & 63;
    const int wv   = tid >> 6;
    const int wr = wv >> 1, wc = wv & 1;
    const int l15 = lane & 15, q = lane >> 4;

    f32x4 acc[2][2] = {};
    const ushort_t* Abase = As + (wr * 32 + l15) * 144 + q * 8;
    const ushort_t* Bbase = Bs + (wc * 32 + l15) * 144 + q * 8;

#pragma unroll
    for (int ks = 0; ks < 4; ks++) {
        short8 a0 = *(const short8*)(Abase + ks * 32);
        short8 a1 = *(const short8*)(Abase + 16 * 144 + ks * 32);
        short8 b0 = *(const short8*)(Bbase + ks * 32);
        short8 b1 = *(const short8*)(Bbase + 16 * 144 + ks * 32);
        acc[0][0] = __builtin_amdgcn_mfma_f32_16x16x32_bf16(a0, b0, acc[0][0], 0, 0, 0);
        acc[0][1] = __builtin_amdgcn_mfma_f32_16x16x32_bf16(a0, b1, acc[0][1], 0, 0, 0);
        acc[1][0] = __builtin_amdgcn_mfma_f32_16x16x32_bf16(a1, b0, acc[1][0], 0, 0, 0);
        acc[1][1] = __builtin_amdgcn_mfma_f32_16x16x32_bf16(a1, b1, acc[1][1], 0, 0, 0);
    }

    // C/D layout: col = lane&15, row = (lane>>4)*4 + reg  [verified m89/m91]
#pragma unroll
    for (int ni = 0; ni < 2; ni++) {
        int c_ = col0 + wc * 32 + ni * 16 + l15;
        float bv = bias[c_];
#pragma unroll
        for (int mi = 0; mi < 2; mi++) {
#pragma unroll
            for (int reg = 0; reg < 4; reg++) {
                int r_ = row0 + wr * 32 + mi * 16 + q * 4 + reg;
                if (r_ < M) out[(size_t)r_ * VOCAB + c_] = acc[mi][ni][reg] + bv;
            }
        }
    }
}

__global__ __launch_bounds__(256) void k_logsoftmax(float* __restrict__ out) {
    const int row = blockIdx.x;
    float4* p4 = (float4*)(out + (size_t)row * VOCAB);
    const int tid = threadIdx.x;
    float4 v[2];
    float m = -INFINITY;
#pragma unroll
    for (int i = 0; i < 2; i++) {
        v[i] = p4[tid + i * 256];
        m = fmaxf(m, fmaxf(fmaxf(v[i].x, v[i].y), fmaxf(v[i].z, v[i].w)));
    }
#pragma unroll
    for (int off = 1; off < 64; off <<= 1) m = fmaxf(m, __shfl_xor(m, off));
    __shared__ float redm[4];
    __shared__ float reds[4];
    int wave = tid >> 6;
    if ((tid & 63) == 0) redm[wave] = m;
    __syncthreads();
    m = fmaxf(fmaxf(redm[0], redm[1]), fmaxf(redm[2], redm[3]));
    float s = 0.0f;
#pragma unroll
    for (int i = 0; i < 2; i++)
        s += expf(v[i].x - m) + expf(v[i].y - m) + expf(v[i].z - m) + expf(v[i].w - m);
#pragma unroll
    for (int off = 1; off < 64; off <<= 1) s += __shfl_xor(s, off);
    if ((tid & 63) == 0) reds[wave] = s;
    __syncthreads();
    s = reds[0] + reds[1] + reds[2] + reds[3];
    float L = m + logf(s);
#pragma unroll
    for (int i = 0; i < 2; i++) {
        float4 o = v[i];
        o.x -= L; o.y -= L; o.z -= L; o.w -= L;
        p4[tid + i * 256] = o;
    }
}

extern "C" void kernel_launch(void* const* d_in, const int* in_sizes, int n_in,
                              void* d_out, int out_size, void* d_ws, size_t ws_size,
                              hipStream_t stream) {
    const int*   x    = (const int*)d_in[0];
    const int*   ei   = (const int*)d_in[1];
    const int*   src  = ei;
    const int*   dst  = ei + N_EDGES;
    const int*   mask = (const int*)d_in[2];
    const float* emb  = (const float*)d_in[3];
    const float* Wl1  = (const float*)d_in[4];
    const float* bl1  = (const float*)d_in[5];
    const float* Wr1  = (const float*)d_in[6];
    const float* Wl2  = (const float*)d_in[7];
    const float* bl2  = (const float*)d_in[8];
    const float* Wr2  = (const float*)d_in[9];
    float* out = (float*)d_out;

    char* ws = (char*)d_ws;
    float*    h1     = (float*)(ws + H1_OFF);
    int*      esrc   = (int*)(ws + ESRC_OFF);
    int*      evoc   = (int*)(ws + EVOC_OFF);
    int2*     e2     = (int2*)(ws + E2_OFF);
    float*    embWl  = (float*)(ws + EWL_OFF);     // aliases e2 (after sortb)
    float*    embWr  = (float*)(ws + EWR_OFF);
    ushort_t* W2T    = (ushort_t*)(ws + W2T_OFF);
    ushort_t* X2b    = (ushort_t*)(ws + X2B_OFF);
    int*      rowptr = (int*)(ws + ROWPTR_OFF);
    int*      bcnt   = (int*)(ws + BCNT_OFF);
    int*      bptr   = (int*)(ws + BPTR_OFF);
    int*      bcur   = (int*)(ws + BCUR_OFF);

    hipMemsetAsync(ws + BCNT_OFF, 0, 2096, stream);          // bucket counts = 0

    // ---- CSR build: bucket partition + per-bucket LDS counting sort ----
    k_count   <<<512, 256, 0, stream>>>(dst, bcnt);
    k_bscan   <<<1, 1024, 0, stream>>>(bcnt, bptr, bcur, rowptr);
    k_scatter2<<<NCH, 256, 0, stream>>>(src, dst, x, bcur, e2);
    k_sortb   <<<NBKT, 256, 0, stream>>>(bptr, e2, rowptr, esrc, evoc);

    // ---- small transformed tables (placed in e2's dead region) ----
    k_prep<<<1088, 256, 0, stream>>>(emb, Wl1, Wr1, Wl2, Wr2, embWl, embWr, W2T);

    // ---- layer 1: node-parallel CSR aggregation, fused epilogue ----
    k_agg1<<<(N_NODES * 64 + 255) / 256, 256, 0, stream>>>(rowptr, evoc, x, embWl, embWr, bl1, h1);

    // ---- layer 2: masked-row gather -> bf16 X2, MFMA GEMM, log_softmax ----
    k_x2<<<(N_MASK * 64 + 255) / 256, 256, 0, stream>>>(mask, rowptr, esrc, h1, X2b);
    dim3 g2((N_MASK + 63) / 64, VOCAB / 64);
    k_gemm2_mfma<<<g2, 256, 0, stream>>>(X2b, W2T, bl2, out, N_MASK);

    k_logsoftmax<<<N_MASK, 256, 0, stream>>>(out);
}